// Round 3
// baseline (920.385 us; speedup 1.0000x reference)
//
#include <hip/hip_runtime.h>
#include <stdint.h>

typedef uint32_t u32;
typedef uint64_t u64;

#define KREN 1000
#define NBLK 256
#define NTHR 256
#define TOT (NBLK * NTHR)
#define ITERS 16            // ceil(1e6 / 65536)
#define CAND_CAP 2048
#define GSTRIDE 12

// monotonic float -> u32 key (larger key == larger float)
__device__ __forceinline__ u32 fkey(float f) {
  u32 b = __float_as_uint(f);
  return (b & 0x80000000u) ? ~b : (b | 0x80000000u);
}

// sense-reversing grid barrier; bar[0]=arrive count, bar[1]=generation.
// Requires all blocks co-resident (cooperative launch). bar zeroed by memset.
__device__ __forceinline__ void grid_sync(u32* bar) {
  __syncthreads();
  if (threadIdx.x == 0) {
    __threadfence();  // publish this block's global writes (agent scope)
    u32 gen = __hip_atomic_load(&bar[1], __ATOMIC_RELAXED, __HIP_MEMORY_SCOPE_AGENT);
    u32 arr = __hip_atomic_fetch_add(&bar[0], 1u, __ATOMIC_ACQ_REL, __HIP_MEMORY_SCOPE_AGENT);
    if (arr == NBLK - 1) {
      __hip_atomic_store(&bar[0], 0u, __ATOMIC_RELAXED, __HIP_MEMORY_SCOPE_AGENT);
      __hip_atomic_store(&bar[1], gen + 1u, __ATOMIC_RELEASE, __HIP_MEMORY_SCOPE_AGENT);
    } else {
      while (__hip_atomic_load(&bar[1], __ATOMIC_ACQUIRE, __HIP_MEMORY_SCOPE_AGENT) == gen) {
        __builtin_amdgcn_s_sleep(2);
      }
    }
    __threadfence();
  }
  __syncthreads();
}

__global__ __launch_bounds__(NTHR) void k_fused(
    const float* __restrict__ pos, const float* __restrict__ scales,
    const float* __restrict__ rot, const float* __restrict__ colors,
    const float* __restrict__ opac, const float* __restrict__ csh,
    const float* __restrict__ cam, const float* __restrict__ campos,
    u32* __restrict__ keys, u32* __restrict__ partial, u32* __restrict__ state,
    u32* __restrict__ bar, u64* __restrict__ cand, u32* __restrict__ order,
    float* __restrict__ gauss, float* __restrict__ out, int N, int shstride) {
  __shared__ u64 smem[6000];  // 48 KB, reused: hist(1KB) / sort(16KB) / render(48KB)
  u32* h = (u32*)smem;
  int tid = threadIdx.x, bid = blockIdx.x;
  int gtid = bid * NTHR + tid;

  // ---------- phase 0: depth keys + hist of byte3 ----------
  h[tid] = 0;
  __syncthreads();
  {
    float c8 = cam[8], c9 = cam[9], c10 = cam[10], c11 = cam[11];
    for (int it = 0; it < ITERS; ++it) {
      int i = gtid + it * TOT;
      if (i < N) {
        float x = pos[3 * i], y = pos[3 * i + 1], z = pos[3 * i + 2];
        u32 mk = fkey(c8 * x + c9 * y + c10 * z + c11);
        keys[i] = mk;
        atomicAdd(&h[mk >> 24], 1u);
      }
    }
  }
  __syncthreads();
  partial[bid * 256 + tid] = h[tid];
  grid_sync(bar);

  // ---------- radix-select: pick / hist / pick / ... ----------
  for (int lvl = 0; lvl < 4; ++lvl) {
    int shift = 24 - 8 * lvl;
    // pick (block 0): sum partials, find bin of K-th largest
    if (bid == 0) {
      u32 cnt = 0;
      for (int b = 0; b < NBLK; ++b) cnt += partial[b * 256 + tid];
      h[tid] = cnt;
      __syncthreads();
      if (tid == 0) {
        u32 K = (lvl == 0) ? (u32)KREN : state[1];
        u32 cum = 0;
        int b = 255;
        for (; b >= 0; --b) { cum += h[b]; if (cum >= K) break; }
        if (b < 0) b = 0;
        u32 above = cum - h[b];
        state[1] = K - above;
        u32 pref = (lvl == 0) ? 0u : state[0];
        state[0] = pref | (((u32)b) << shift);
        if (lvl == 3) state[2] = 0u;  // collect ticket
      }
    }
    grid_sync(bar);
    if (lvl == 3) break;
    // hist of next byte among prefix-matching keys
    h[tid] = 0;
    __syncthreads();
    {
      u32 pref = state[0];
      int nshift = shift - 8;
      u32 mask = ~((1u << (nshift + 8)) - 1u);
      for (int it = 0; it < ITERS; ++it) {
        int i = gtid + it * TOT;
        if (i < N) {
          u32 k = keys[i];
          if ((k & mask) == pref) atomicAdd(&h[(k >> nshift) & 255u], 1u);
        }
      }
    }
    __syncthreads();
    partial[bid * 256 + tid] = h[tid];
    grid_sync(bar);
  }

  // ---------- collect candidates with key >= threshold ----------
  {
    u32 T = state[0];
    for (int it = 0; it < ITERS; ++it) {
      int i = gtid + it * TOT;
      if (i < N) {
        u32 k = keys[i];
        if (k >= T) {
          u32 p = atomicAdd(&state[2], 1u);
          if (p < CAND_CAP) cand[p] = (((u64)(~k)) << 32) | (u32)i;
        }
      }
    }
  }
  grid_sync(bar);

  // ---------- block 0: bitonic sort (depth desc, index asc), emit order ----------
  if (bid == 0) {
    u64* s = smem;
    int M = (int)state[2];
    if (M > CAND_CAP) M = CAND_CAP;
    for (int i = tid; i < CAND_CAP; i += NTHR) s[i] = (i < M) ? cand[i] : ~0ull;
    __syncthreads();
    for (int k = 2; k <= CAND_CAP; k <<= 1) {
      for (int j = k >> 1; j > 0; j >>= 1) {
        for (int t = tid; t < CAND_CAP; t += NTHR) {
          int ixj = t ^ j;
          if (ixj > t) {
            u64 a = s[t], b = s[ixj];
            bool up = ((t & k) == 0);
            if (up ? (a > b) : (a < b)) { s[t] = b; s[ixj] = a; }
          }
        }
        __syncthreads();
      }
    }
    for (int i = tid; i < KREN; i += NTHR) order[i] = (u32)(s[i] & 0xffffffffu);
  }
  grid_sync(bar);

  // ---------- prep top-K gaussians (threads 0..999 across blocks 0..3) ----------
  if (gtid < KREN) {
    int g = (int)order[gtid];
    float x = pos[3 * g], y = pos[3 * g + 1], z = pos[3 * g + 2];
    float c0 = cam[0], c1 = cam[1], c2 = cam[2], c3 = cam[3];
    float c4 = cam[4], c5 = cam[5], c6 = cam[6], c7 = cam[7];
    float c8 = cam[8], c9 = cam[9], c10 = cam[10], c11 = cam[11];
    float dep = c8 * x + c9 * y + c10 * z + c11;
    float invd = 1.0f / (dep + 1e-7f);
    float p2x = (c0 * x + c1 * y + c2 * z + c3) * invd;
    float p2y = (c4 * x + c5 * y + c6 * z + c7) * invd;
    float qw = rot[4 * g], qx = rot[4 * g + 1], qy = rot[4 * g + 2], qz = rot[4 * g + 3];
    float qn = rsqrtf(qw * qw + qx * qx + qy * qy + qz * qz);
    qw *= qn; qx *= qn; qy *= qn; qz *= qn;
    float r00 = 1.f - 2.f * (qy * qy + qz * qz), r01 = 2.f * (qx * qy - qw * qz), r02 = 2.f * (qx * qz + qw * qy);
    float r10 = 2.f * (qx * qy + qw * qz), r11 = 1.f - 2.f * (qx * qx + qz * qz), r12 = 2.f * (qy * qz - qw * qx);
    float r20 = 2.f * (qx * qz - qw * qy), r21 = 2.f * (qy * qz + qw * qx), r22 = 1.f - 2.f * (qx * qx + qy * qy);
    float e0 = fmaxf(expf(scales[3 * g]), 1e-7f);
    float e1 = fmaxf(expf(scales[3 * g + 1]), 1e-7f);
    float e2 = fmaxf(expf(scales[3 * g + 2]), 1e-7f);
    float v0 = e0 * e0, v1 = e1 * e1, v2 = e2 * e2;
    float C00 = r00 * r00 * v0 + r01 * r01 * v1 + r02 * r02 * v2;
    float C01 = r00 * r10 * v0 + r01 * r11 * v1 + r02 * r12 * v2;
    float C02 = r00 * r20 * v0 + r01 * r21 * v1 + r02 * r22 * v2;
    float C11 = r10 * r10 * v0 + r11 * r11 * v1 + r12 * r12 * v2;
    float C12 = r10 * r20 * v0 + r11 * r21 * v1 + r12 * r22 * v2;
    float C22 = r20 * r20 * v0 + r21 * r21 * v1 + r22 * r22 * v2;
    float fx = c0, fy = c5;
    float jd = 1.0f / dep;
    float j0 = fx * jd, j2 = -fx * p2x * jd, j4 = fy * jd, j5 = -fy * p2y * jd;
    float u0x = j0 * C00 + j2 * C02;
    float u0y = j0 * C01 + j2 * C12;
    float u0z = j0 * C02 + j2 * C22;
    float u1y = j4 * C11 + j5 * C12;
    float u1z = j4 * C12 + j5 * C22;
    float a = u0x * j0 + u0z * j2 + 1e-6f;
    float b = u0y * j4 + u0z * j5;
    float d2 = u1y * j4 + u1z * j5 + 1e-6f;
    float det = a * d2 - b * b;
    float idet = 1.0f / det;
    const float L = 1.4426950408889634f;
    float Aq = -0.5f * L * d2 * idet;
    float Bq = L * b * idet;
    float Cq = -0.5f * L * a * idet;
    float vx = x - campos[0], vy = y - campos[1], vz = z - campos[2];
    float vn = rsqrtf(vx * vx + vy * vy + vz * vz);
    vx *= vn; vy *= vn; vz *= vn;
    float sh[9];
    sh[0] = 0.28209479177387814f;
    sh[1] = -0.48860251190291987f * vy;
    sh[2] = 0.48860251190291987f * vz;
    sh[3] = -0.48860251190291987f * vx;
    sh[4] = 1.0925484305920792f * vx * vy;
    sh[5] = -1.0925484305920792f * vy * vz;
    sh[6] = 0.31539156525252005f * (2.f * vz * vz - vx * vx - vy * vy);
    sh[7] = -1.0925484305920792f * vx * vz;
    sh[8] = 0.5462742152960396f * (vx * vx - vy * vy);
    float col[3];
    for (int c = 0; c < 3; ++c) {
      float accv = colors[3 * g + c];
      for (int k2 = 0; k2 < 9; ++k2) accv += sh[k2] * csh[(size_t)g * shstride + 3 * k2 + c];
      col[c] = 1.0f / (1.0f + __expf(-accv));
    }
    float op = 1.0f / (1.0f + __expf(-opac[g]));
    float* G = gauss + gtid * GSTRIDE;
    G[0] = p2x; G[1] = p2y; G[2] = Aq; G[3] = Bq; G[4] = Cq;
    G[5] = op;  G[6] = col[0]; G[7] = col[1]; G[8] = col[2];
    G[9] = 0.f; G[10] = 0.f; G[11] = 0.f;
  }
  grid_sync(bar);

  // ---------- render: one thread per pixel, gaussians staged in LDS ----------
  {
    float* gs = (float*)smem;
    for (int i = tid; i < KREN * GSTRIDE; i += NTHR) gs[i] = gauss[i];
    __syncthreads();
    int p = gtid;
    float px = (float)(p & 255);
    float py = (float)(p >> 8);
    float cr = 0.f, cg = 0.f, cb = 0.f, acc = 0.f;
    for (int k = 0; k < KREN; ++k) {
      const float4* G = (const float4*)(gs + k * GSTRIDE);
      float4 g0 = G[0];
      float4 g1 = G[1];
      float g2x = gs[k * GSTRIDE + 8];
      float dx = px - g0.x, dy = py - g0.y;
      float sE = g0.z * dx * dx + g0.w * dx * dy + g1.x * dy * dy;
      float alpha = g1.y * exp2f(sE);
      float w = (1.0f - acc) * alpha;
      cr += w * g1.z; cg += w * g1.w; cb += w * g2x;
      acc += w;
    }
    out[3 * p + 0] = cr;
    out[3 * p + 1] = cg;
    out[3 * p + 2] = cb;
  }
}

extern "C" void kernel_launch(void* const* d_in, const int* in_sizes, int n_in,
                              void* d_out, int out_size, void* d_ws, size_t ws_size,
                              hipStream_t stream) {
  const float* positions = (const float*)d_in[0];
  const float* scales    = (const float*)d_in[1];
  const float* rotations = (const float*)d_in[2];
  const float* colors    = (const float*)d_in[3];
  const float* opacity   = (const float*)d_in[4];
  const float* colors_sh = (const float*)d_in[5];
  const float* cam       = (const float*)d_in[6];
  const float* campos    = (const float*)d_in[7];
  int N = in_sizes[0] / 3;
  int shstride = in_sizes[5] / N;  // 48

  char* ws = (char*)d_ws;
  u32* keys    = (u32*)ws;                          // 4 MB region
  u32* partial = (u32*)(ws + 4194304);              // 256 KB
  u32* state   = (u32*)(ws + 4456448);              // 256 B
  u32* bar     = (u32*)(ws + 4456704);              // 256 B
  u64* cand    = (u64*)(ws + 4456960);              // 16 KB
  u32* order   = (u32*)(ws + 4473344);              // 4 KB
  float* gauss = (float*)(ws + 4477440);            // 48 KB
  float* out   = (float*)d_out;

  // barrier counters must start at 0 (ws is poisoned 0xAA)
  hipMemsetAsync(bar, 0, 256, stream);

  void* args[] = {(void*)&positions, (void*)&scales, (void*)&rotations, (void*)&colors,
                  (void*)&opacity, (void*)&colors_sh, (void*)&cam, (void*)&campos,
                  (void*)&keys, (void*)&partial, (void*)&state, (void*)&bar,
                  (void*)&cand, (void*)&order, (void*)&gauss, (void*)&out,
                  (void*)&N, (void*)&shstride};
  hipLaunchCooperativeKernel((const void*)k_fused, dim3(NBLK), dim3(NTHR), args, 0, stream);
}

// Round 4
// 535.966 us; speedup vs baseline: 1.7172x; 1.7172x over previous
//
#include <hip/hip_runtime.h>
#include <stdint.h>

typedef uint32_t u32;
typedef uint64_t u64;

#define KREN 1000
#define NBLK 256
#define NTHR 256
#define TOT (NBLK * NTHR)
#define ITERS 16            // ceil(1e6 / 65536)
#define CAND_CAP 4096
#define GSTRIDE 12

// monotonic float -> u32 key (larger key == larger float)
__device__ __forceinline__ u32 fkey(float f) {
  u32 b = __float_as_uint(f);
  return (b & 0x80000000u) ? ~b : (b | 0x80000000u);
}

// sense-reversing grid barrier; bar[0]=arrive count, bar[1]=generation.
__device__ __forceinline__ void grid_sync(u32* bar) {
  __syncthreads();
  if (threadIdx.x == 0) {
    __threadfence();
    u32 gen = __hip_atomic_load(&bar[1], __ATOMIC_RELAXED, __HIP_MEMORY_SCOPE_AGENT);
    u32 arr = __hip_atomic_fetch_add(&bar[0], 1u, __ATOMIC_ACQ_REL, __HIP_MEMORY_SCOPE_AGENT);
    if (arr == NBLK - 1) {
      __hip_atomic_store(&bar[0], 0u, __ATOMIC_RELAXED, __HIP_MEMORY_SCOPE_AGENT);
      __hip_atomic_store(&bar[1], gen + 1u, __ATOMIC_RELEASE, __HIP_MEMORY_SCOPE_AGENT);
    } else {
      while (__hip_atomic_load(&bar[1], __ATOMIC_ACQUIRE, __HIP_MEMORY_SCOPE_AGENT) == gen) {
        __builtin_amdgcn_s_sleep(4);
      }
    }
    __threadfence();
  }
  __syncthreads();
}

// Block-redundant pick over a 4096-bin global hist: find bin where the
// descending (suffix) cumulative count first reaches K. Every block computes
// the identical result (pure u32 adds -> deterministic). lds needs 258 u32.
__device__ __forceinline__ void pick_scan(const u32* __restrict__ hist, u32 K,
                                          u32* lds, int* bin_out, u32* Krem_out) {
  int tid = threadIdx.x;
  u32 hv[16];
  u32 s = 0;
#pragma unroll
  for (int k = 0; k < 16; ++k) { hv[k] = hist[tid * 16 + k]; s += hv[k]; }
  lds[tid] = s;
  __syncthreads();
  // Hillis-Steele inclusive suffix sum over 256 chunk sums
  for (int d = 1; d < 256; d <<= 1) {
    u32 v = lds[tid] + ((tid + d < 256) ? lds[tid + d] : 0u);
    __syncthreads();
    lds[tid] = v;
    __syncthreads();
  }
  u32 inc = lds[tid];
  u32 above = (tid < 255) ? lds[tid + 1] : 0u;
  if (above < K && inc >= K) {   // unique crossing chunk
    u32 cum = above;
    for (int k = 15; k >= 0; --k) {
      cum += hv[k];
      if (cum >= K) {
        lds[256] = (u32)(tid * 16 + k);
        lds[257] = K - (cum - hv[k]);
        break;
      }
    }
  }
  __syncthreads();
  *bin_out = (int)lds[256];
  *Krem_out = lds[257];
  __syncthreads();  // callers reuse lds
}

__global__ __launch_bounds__(NTHR) void k_fused(
    const float* __restrict__ pos, const float* __restrict__ scales,
    const float* __restrict__ rot, const float* __restrict__ colors,
    const float* __restrict__ opac, const float* __restrict__ csh,
    const float* __restrict__ cam, const float* __restrict__ campos,
    u32* __restrict__ keys, u64* __restrict__ cand, float* __restrict__ gauss,
    u32* __restrict__ hist1, u32* __restrict__ hist2, u32* __restrict__ state,
    u32* __restrict__ bar, float* __restrict__ out, int N, int shstride) {
  __shared__ u64 smem[6144];  // 48 KB: hist(16KB) / cand-stage(32KB) / render(48KB)
  u32* hl = (u32*)smem;
  int tid = threadIdx.x, bid = blockIdx.x;
  int gtid = bid * NTHR + tid;

  // ---------- P0: depth keys + 12-bit LDS hist + sparse global flush ----------
  for (int i = tid; i < 4096; i += NTHR) hl[i] = 0;
  __syncthreads();
  {
    float c8 = cam[8], c9 = cam[9], c10 = cam[10], c11 = cam[11];
    for (int it = 0; it < ITERS; ++it) {
      int i = gtid + it * TOT;
      if (i < N) {
        float x = pos[3 * i], y = pos[3 * i + 1], z = pos[3 * i + 2];
        u32 mk = fkey(c8 * x + c9 * y + c10 * z + c11);
        keys[i] = mk;
        atomicAdd(&hl[mk >> 20], 1u);
      }
    }
  }
  __syncthreads();
  for (int i = tid; i < 4096; i += NTHR) {
    u32 v = hl[i];
    if (v) atomicAdd(&hist1[i], v);
  }
  grid_sync(bar);

  // ---------- P1: pick level-1 bin (redundant) + level-2 hist ----------
  int bin1; u32 K1;
  pick_scan(hist1, (u32)KREN, hl, &bin1, &K1);
  u32 pref = (u32)bin1;
  for (int i = tid; i < 4096; i += NTHR) hl[i] = 0;
  __syncthreads();
  for (int it = 0; it < ITERS; ++it) {
    int i = gtid + it * TOT;
    if (i < N) {
      u32 k = keys[i];
      if ((k >> 20) == pref) atomicAdd(&hl[(k >> 8) & 4095u], 1u);
    }
  }
  __syncthreads();
  for (int i = tid; i < 4096; i += NTHR) {
    u32 v = hl[i];
    if (v) atomicAdd(&hist2[i], v);
  }
  grid_sync(bar);

  // ---------- P2: pick level-2 bin (redundant) + collect ----------
  int bin2; u32 K2;
  pick_scan(hist2, K1, hl, &bin2, &K2);
  {
    u32 T = (pref << 20) | (((u32)bin2) << 8);
    for (int it = 0; it < ITERS; ++it) {
      int i = gtid + it * TOT;
      if (i < N) {
        u32 k = keys[i];
        if (k >= T) {
          u32 p = atomicAdd(&state[0], 1u);
          if (p < CAND_CAP) cand[p] = (((u64)(~k)) << 32) | (u32)i;
        }
      }
    }
  }
  grid_sync(bar);

  // ---------- P3: parallel rank (O(M^2), LDS broadcast) + prep ----------
  if (bid < CAND_CAP / NTHR) {
    u64* s = smem;
    int M = (int)state[0];
    if (M > CAND_CAP) M = CAND_CAP;
    for (int i = tid; i < M; i += NTHR) s[i] = cand[i];
    __syncthreads();
    int i = gtid;
    if (i < M) {
      u64 mine = s[i];
      int r = 0;
      for (int j = 0; j < M; ++j) r += (s[j] < mine) ? 1 : 0;
      if (r < KREN) {
        int g = (int)(u32)(mine & 0xffffffffu);
        float x = pos[3 * g], y = pos[3 * g + 1], z = pos[3 * g + 2];
        float c0 = cam[0], c1 = cam[1], c2 = cam[2], c3 = cam[3];
        float c4 = cam[4], c5 = cam[5], c6 = cam[6], c7 = cam[7];
        float c8 = cam[8], c9 = cam[9], c10 = cam[10], c11 = cam[11];
        float dep = c8 * x + c9 * y + c10 * z + c11;
        float invd = 1.0f / (dep + 1e-7f);
        float p2x = (c0 * x + c1 * y + c2 * z + c3) * invd;
        float p2y = (c4 * x + c5 * y + c6 * z + c7) * invd;
        float qw = rot[4 * g], qx = rot[4 * g + 1], qy = rot[4 * g + 2], qz = rot[4 * g + 3];
        float qn = rsqrtf(qw * qw + qx * qx + qy * qy + qz * qz);
        qw *= qn; qx *= qn; qy *= qn; qz *= qn;
        float r00 = 1.f - 2.f * (qy * qy + qz * qz), r01 = 2.f * (qx * qy - qw * qz), r02 = 2.f * (qx * qz + qw * qy);
        float r10 = 2.f * (qx * qy + qw * qz), r11 = 1.f - 2.f * (qx * qx + qz * qz), r12 = 2.f * (qy * qz - qw * qx);
        float r20 = 2.f * (qx * qz - qw * qy), r21 = 2.f * (qy * qz + qw * qx), r22 = 1.f - 2.f * (qx * qx + qy * qy);
        float e0 = fmaxf(expf(scales[3 * g]), 1e-7f);
        float e1 = fmaxf(expf(scales[3 * g + 1]), 1e-7f);
        float e2 = fmaxf(expf(scales[3 * g + 2]), 1e-7f);
        float v0 = e0 * e0, v1 = e1 * e1, v2 = e2 * e2;
        float C00 = r00 * r00 * v0 + r01 * r01 * v1 + r02 * r02 * v2;
        float C01 = r00 * r10 * v0 + r01 * r11 * v1 + r02 * r12 * v2;
        float C02 = r00 * r20 * v0 + r01 * r21 * v1 + r02 * r22 * v2;
        float C11 = r10 * r10 * v0 + r11 * r11 * v1 + r12 * r12 * v2;
        float C12 = r10 * r20 * v0 + r11 * r21 * v1 + r12 * r22 * v2;
        float C22 = r20 * r20 * v0 + r21 * r21 * v1 + r22 * r22 * v2;
        float fx = c0, fy = c5;
        float jd = 1.0f / dep;
        float j0 = fx * jd, j2 = -fx * p2x * jd, j4 = fy * jd, j5 = -fy * p2y * jd;
        float u0x = j0 * C00 + j2 * C02;
        float u0y = j0 * C01 + j2 * C12;
        float u0z = j0 * C02 + j2 * C22;
        float u1y = j4 * C11 + j5 * C12;
        float u1z = j4 * C12 + j5 * C22;
        float a = u0x * j0 + u0z * j2 + 1e-6f;
        float b = u0y * j4 + u0z * j5;
        float d2 = u1y * j4 + u1z * j5 + 1e-6f;
        float det = a * d2 - b * b;
        float idet = 1.0f / det;
        const float L = 1.4426950408889634f;
        float Aq = -0.5f * L * d2 * idet;
        float Bq = L * b * idet;
        float Cq = -0.5f * L * a * idet;
        float vx = x - campos[0], vy = y - campos[1], vz = z - campos[2];
        float vn = rsqrtf(vx * vx + vy * vy + vz * vz);
        vx *= vn; vy *= vn; vz *= vn;
        float sh[9];
        sh[0] = 0.28209479177387814f;
        sh[1] = -0.48860251190291987f * vy;
        sh[2] = 0.48860251190291987f * vz;
        sh[3] = -0.48860251190291987f * vx;
        sh[4] = 1.0925484305920792f * vx * vy;
        sh[5] = -1.0925484305920792f * vy * vz;
        sh[6] = 0.31539156525252005f * (2.f * vz * vz - vx * vx - vy * vy);
        sh[7] = -1.0925484305920792f * vx * vz;
        sh[8] = 0.5462742152960396f * (vx * vx - vy * vy);
        float col[3];
        for (int c = 0; c < 3; ++c) {
          float accv = colors[3 * g + c];
          for (int k2 = 0; k2 < 9; ++k2) accv += sh[k2] * csh[(size_t)g * shstride + 3 * k2 + c];
          col[c] = 1.0f / (1.0f + __expf(-accv));
        }
        float op = 1.0f / (1.0f + __expf(-opac[g]));
        float* G = gauss + r * GSTRIDE;
        G[0] = p2x; G[1] = p2y; G[2] = Aq; G[3] = Bq; G[4] = Cq;
        G[5] = op;  G[6] = col[0]; G[7] = col[1]; G[8] = col[2];
        G[9] = 0.f; G[10] = 0.f; G[11] = 0.f;
      }
    }
  }
  grid_sync(bar);

  // ---------- P4: render, gaussians staged in LDS ----------
  {
    float* gs = (float*)smem;
    for (int i = tid; i < KREN * GSTRIDE; i += NTHR) gs[i] = gauss[i];
    __syncthreads();
    int p = gtid;
    float px = (float)(p & 255);
    float py = (float)(p >> 8);
    float cr = 0.f, cg = 0.f, cb = 0.f, acc = 0.f;
    for (int k = 0; k < KREN; ++k) {
      const float4* G = (const float4*)(gs + k * GSTRIDE);
      float4 g0 = G[0];
      float4 g1 = G[1];
      float g2x = gs[k * GSTRIDE + 8];
      float dx = px - g0.x, dy = py - g0.y;
      float sE = g0.z * dx * dx + g0.w * dx * dy + g1.x * dy * dy;
      float alpha = g1.y * exp2f(sE);
      float w = (1.0f - acc) * alpha;
      cr += w * g1.z; cg += w * g1.w; cb += w * g2x;
      acc += w;
    }
    out[3 * p + 0] = cr;
    out[3 * p + 1] = cg;
    out[3 * p + 2] = cb;
  }
}

extern "C" void kernel_launch(void* const* d_in, const int* in_sizes, int n_in,
                              void* d_out, int out_size, void* d_ws, size_t ws_size,
                              hipStream_t stream) {
  const float* positions = (const float*)d_in[0];
  const float* scales    = (const float*)d_in[1];
  const float* rotations = (const float*)d_in[2];
  const float* colors    = (const float*)d_in[3];
  const float* opacity   = (const float*)d_in[4];
  const float* colors_sh = (const float*)d_in[5];
  const float* cam       = (const float*)d_in[6];
  const float* campos    = (const float*)d_in[7];
  int N = in_sizes[0] / 3;
  int shstride = in_sizes[5] / N;  // 48

  char* ws = (char*)d_ws;
  u32* keys    = (u32*)ws;                      // 4 MB
  u64* cand    = (u64*)(ws + 4194304);          // 32 KB
  float* gauss = (float*)(ws + 4227072);        // 48 KB (padded to 49152)
  char* zr     = ws + 4276224;                  // zeroed region, 33280 B
  u32* hist1   = (u32*)zr;                      // 16 KB
  u32* hist2   = (u32*)(zr + 16384);            // 16 KB
  u32* state   = (u32*)(zr + 32768);            // 256 B
  u32* bar     = (u32*)(zr + 33024);            // 256 B
  float* out   = (float*)d_out;

  hipMemsetAsync(zr, 0, 33280, stream);

  void* args[] = {(void*)&positions, (void*)&scales, (void*)&rotations, (void*)&colors,
                  (void*)&opacity, (void*)&colors_sh, (void*)&cam, (void*)&campos,
                  (void*)&keys, (void*)&cand, (void*)&gauss,
                  (void*)&hist1, (void*)&hist2, (void*)&state, (void*)&bar,
                  (void*)&out, (void*)&N, (void*)&shstride};
  hipLaunchCooperativeKernel((const void*)k_fused, dim3(NBLK), dim3(NTHR), args, 0, stream);
}

// Round 5
// 448.570 us; speedup vs baseline: 2.0518x; 1.1948x over previous
//
#include <hip/hip_runtime.h>
#include <stdint.h>

typedef uint32_t u32;
typedef uint64_t u64;

#define KREN 1000
#define NBLK 256
#define NTHR 1024
#define TOT (NBLK * NTHR)
#define CAND_CAP 4096
#define GSTRIDE 12
#define SEGN 4              // render: gaussian segments per pixel
#define KPER (KREN / SEGN)  // 250

// monotonic float -> u32 key (larger key == larger float)
__device__ __forceinline__ u32 fkey(float f) {
  u32 b = __float_as_uint(f);
  return (b & 0x80000000u) ? ~b : (b | 0x80000000u);
}

// Grid barrier. RELAXED spin (no per-poll cache invalidate), RELEASE on the
// arrive-add (publishes this block's plain stores), ONE acquire fence after
// wakeup (invalidate local caches once so cross-block data is fresh).
__device__ __forceinline__ void grid_sync(u32* bar) {
  __syncthreads();
  if (threadIdx.x == 0) {
    u32 gen = __hip_atomic_load(&bar[1], __ATOMIC_RELAXED, __HIP_MEMORY_SCOPE_AGENT);
    u32 arr = __hip_atomic_fetch_add(&bar[0], 1u, __ATOMIC_RELEASE, __HIP_MEMORY_SCOPE_AGENT);
    if (arr == NBLK - 1) {
      __hip_atomic_store(&bar[0], 0u, __ATOMIC_RELAXED, __HIP_MEMORY_SCOPE_AGENT);
      __hip_atomic_store(&bar[1], gen + 1u, __ATOMIC_RELEASE, __HIP_MEMORY_SCOPE_AGENT);
    } else {
      while (__hip_atomic_load(&bar[1], __ATOMIC_RELAXED, __HIP_MEMORY_SCOPE_AGENT) == gen)
        __builtin_amdgcn_s_sleep(4);
    }
    __builtin_amdgcn_fence(__ATOMIC_ACQUIRE, "agent");
  }
  __syncthreads();
}

// Block-redundant pick over a 4096-bin global hist (4 bins/thread at NTHR=1024).
// Finds bin where descending cumulative count first reaches K. Deterministic.
__device__ __forceinline__ void pick_scan(const u32* __restrict__ hist, u32 K,
                                          u32* lds, int* bin_out, u32* Krem_out) {
  int tid = threadIdx.x;
  u32 hv[4];
  u32 s = 0;
#pragma unroll
  for (int k = 0; k < 4; ++k) { hv[k] = hist[tid * 4 + k]; s += hv[k]; }
  lds[tid] = s;
  __syncthreads();
  for (int d = 1; d < NTHR; d <<= 1) {  // inclusive suffix sum
    u32 v = lds[tid] + ((tid + d < NTHR) ? lds[tid + d] : 0u);
    __syncthreads();
    lds[tid] = v;
    __syncthreads();
  }
  u32 inc = lds[tid];
  u32 above = (tid < NTHR - 1) ? lds[tid + 1] : 0u;
  if (above < K && inc >= K) {  // unique crossing chunk
    u32 cum = above;
    for (int k = 3; k >= 0; --k) {
      cum += hv[k];
      if (cum >= K) {
        lds[NTHR] = (u32)(tid * 4 + k);
        lds[NTHR + 1] = K - (cum - hv[k]);
        break;
      }
    }
  }
  __syncthreads();
  *bin_out = (int)lds[NTHR];
  *Krem_out = lds[NTHR + 1];
  __syncthreads();
}

__global__ __launch_bounds__(NTHR) void k_fused(
    const float* __restrict__ pos, const float* __restrict__ scales,
    const float* __restrict__ rot, const float* __restrict__ colors,
    const float* __restrict__ opac, const float* __restrict__ csh,
    const float* __restrict__ cam, const float* __restrict__ campos,
    u32* __restrict__ keys, u64* __restrict__ cand, float* __restrict__ gauss,
    u32* __restrict__ hist1, u32* __restrict__ hist2, u32* __restrict__ state,
    u32* __restrict__ bar, float* __restrict__ out, int N, int shstride) {
  __shared__ u64 smem[8192];  // 64 KB: hist(16K) / scan(4.1K) / cand(32K) / render(48K+16K)
  u32* hl = (u32*)smem;
  int tid = threadIdx.x, bid = blockIdx.x;
  int gtid = bid * NTHR + tid;

  // ---------- P0: depth keys + 12-bit LDS hist (wave-aggregated) ----------
  for (int i = tid; i < 4096; i += NTHR) hl[i] = 0;
  __syncthreads();
  {
    float c8 = cam[8], c9 = cam[9], c10 = cam[10], c11 = cam[11];
    for (int i = gtid; i < N; i += TOT) {
      float x = pos[3 * i], y = pos[3 * i + 1], z = pos[3 * i + 2];
      u32 mk = fkey(c8 * x + c9 * y + c10 * z + c11);
      keys[i] = mk;
      u32 bin = mk >> 20;
      u64 todo = __ballot(true);  // keys are heavily concentrated: ~few bins/wave
      while (todo) {
        int leader = __ffsll((unsigned long long)todo) - 1;
        u32 lbin = __shfl(bin, leader, 64);
        u64 same = __ballot(bin == lbin);
        if ((int)(tid & 63) == leader) atomicAdd(&hl[lbin], (u32)__popcll(same & todo));
        todo &= ~same;
      }
    }
  }
  __syncthreads();
  for (int i = tid; i < 4096; i += NTHR) {
    u32 v = hl[i];
    if (v) atomicAdd(&hist1[i], v);
  }
  grid_sync(bar);

  // ---------- P1: pick level-1 bin (redundant) + level-2 hist ----------
  int bin1; u32 K1;
  pick_scan(hist1, (u32)KREN, hl, &bin1, &K1);
  u32 pref = (u32)bin1;
  for (int i = tid; i < 4096; i += NTHR) hl[i] = 0;
  __syncthreads();
  for (int i = gtid; i < N; i += TOT) {
    u32 k = keys[i];
    if ((k >> 20) == pref) atomicAdd(&hl[(k >> 8) & 4095u], 1u);
  }
  __syncthreads();
  for (int i = tid; i < 4096; i += NTHR) {
    u32 v = hl[i];
    if (v) atomicAdd(&hist2[i], v);
  }
  grid_sync(bar);

  // ---------- P2: pick level-2 bin (redundant) + collect ----------
  int bin2; u32 K2;
  pick_scan(hist2, K1, hl, &bin2, &K2);
  {
    u32 T = (pref << 20) | (((u32)bin2) << 8);
    for (int i = gtid; i < N; i += TOT) {
      u32 k = keys[i];
      if (k >= T) {
        u32 p = atomicAdd(&state[0], 1u);
        if (p < CAND_CAP) cand[p] = (((u64)(~k)) << 32) | (u32)i;
      }
    }
  }
  grid_sync(bar);

  // ---------- P3: parallel rank (O(M^2), LDS broadcast) + prep ----------
  if (bid < CAND_CAP / NTHR) {
    u64* s = smem;
    int M = (int)state[0];
    if (M > CAND_CAP) M = CAND_CAP;
    for (int i = tid; i < M; i += NTHR) s[i] = cand[i];
    __syncthreads();
    int i = gtid;
    if (i < M) {
      u64 mine = s[i];
      int r = 0;
      for (int j = 0; j < M; ++j) r += (s[j] < mine) ? 1 : 0;
      if (r < KREN) {
        int g = (int)(u32)(mine & 0xffffffffu);
        float x = pos[3 * g], y = pos[3 * g + 1], z = pos[3 * g + 2];
        float c0 = cam[0], c1 = cam[1], c2 = cam[2], c3 = cam[3];
        float c4 = cam[4], c5 = cam[5], c6 = cam[6], c7 = cam[7];
        float c8 = cam[8], c9 = cam[9], c10 = cam[10], c11 = cam[11];
        float dep = c8 * x + c9 * y + c10 * z + c11;
        float invd = 1.0f / (dep + 1e-7f);
        float p2x = (c0 * x + c1 * y + c2 * z + c3) * invd;
        float p2y = (c4 * x + c5 * y + c6 * z + c7) * invd;
        float qw = rot[4 * g], qx = rot[4 * g + 1], qy = rot[4 * g + 2], qz = rot[4 * g + 3];
        float qn = rsqrtf(qw * qw + qx * qx + qy * qy + qz * qz);
        qw *= qn; qx *= qn; qy *= qn; qz *= qn;
        float r00 = 1.f - 2.f * (qy * qy + qz * qz), r01 = 2.f * (qx * qy - qw * qz), r02 = 2.f * (qx * qz + qw * qy);
        float r10 = 2.f * (qx * qy + qw * qz), r11 = 1.f - 2.f * (qx * qx + qz * qz), r12 = 2.f * (qy * qz - qw * qx);
        float r20 = 2.f * (qx * qz - qw * qy), r21 = 2.f * (qy * qz + qw * qx), r22 = 1.f - 2.f * (qx * qx + qy * qy);
        float e0 = fmaxf(expf(scales[3 * g]), 1e-7f);
        float e1 = fmaxf(expf(scales[3 * g + 1]), 1e-7f);
        float e2 = fmaxf(expf(scales[3 * g + 2]), 1e-7f);
        float v0 = e0 * e0, v1 = e1 * e1, v2 = e2 * e2;
        float C00 = r00 * r00 * v0 + r01 * r01 * v1 + r02 * r02 * v2;
        float C01 = r00 * r10 * v0 + r01 * r11 * v1 + r02 * r12 * v2;
        float C02 = r00 * r20 * v0 + r01 * r21 * v1 + r02 * r22 * v2;
        float C11 = r10 * r10 * v0 + r11 * r11 * v1 + r12 * r12 * v2;
        float C12 = r10 * r20 * v0 + r11 * r21 * v1 + r12 * r22 * v2;
        float C22 = r20 * r20 * v0 + r21 * r21 * v1 + r22 * r22 * v2;
        float fx = c0, fy = c5;
        float jd = 1.0f / dep;
        float j0 = fx * jd, j2 = -fx * p2x * jd, j4 = fy * jd, j5 = -fy * p2y * jd;
        float u0x = j0 * C00 + j2 * C02;
        float u0y = j0 * C01 + j2 * C12;
        float u0z = j0 * C02 + j2 * C22;
        float u1y = j4 * C11 + j5 * C12;
        float u1z = j4 * C12 + j5 * C22;
        float a = u0x * j0 + u0z * j2 + 1e-6f;
        float b = u0y * j4 + u0z * j5;
        float d2 = u1y * j4 + u1z * j5 + 1e-6f;
        float det = a * d2 - b * b;
        float idet = 1.0f / det;
        const float L = 1.4426950408889634f;
        float Aq = -0.5f * L * d2 * idet;
        float Bq = L * b * idet;
        float Cq = -0.5f * L * a * idet;
        float vx = x - campos[0], vy = y - campos[1], vz = z - campos[2];
        float vn = rsqrtf(vx * vx + vy * vy + vz * vz);
        vx *= vn; vy *= vn; vz *= vn;
        float sh[9];
        sh[0] = 0.28209479177387814f;
        sh[1] = -0.48860251190291987f * vy;
        sh[2] = 0.48860251190291987f * vz;
        sh[3] = -0.48860251190291987f * vx;
        sh[4] = 1.0925484305920792f * vx * vy;
        sh[5] = -1.0925484305920792f * vy * vz;
        sh[6] = 0.31539156525252005f * (2.f * vz * vz - vx * vx - vy * vy);
        sh[7] = -1.0925484305920792f * vx * vz;
        sh[8] = 0.5462742152960396f * (vx * vx - vy * vy);
        float col[3];
        for (int c = 0; c < 3; ++c) {
          float accv = colors[3 * g + c];
          for (int k2 = 0; k2 < 9; ++k2) accv += sh[k2] * csh[(size_t)g * shstride + 3 * k2 + c];
          col[c] = 1.0f / (1.0f + __expf(-accv));
        }
        float op = 1.0f / (1.0f + __expf(-opac[g]));
        float* G = gauss + r * GSTRIDE;
        G[0] = p2x; G[1] = p2y; G[2] = Aq; G[3] = Bq; G[4] = Cq;
        G[5] = op;  G[6] = col[0]; G[7] = col[1]; G[8] = col[2];
        G[9] = 0.f; G[10] = 0.f; G[11] = 0.f;
      }
    }
  }
  grid_sync(bar);

  // ---------- P4: render, segment-parallel over gaussians ----------
  {
    float* gs = (float*)smem;           // 12000 floats
    float* comb = gs + 12000;           // 4096 floats: (Cr,Cg,Cb,T) per (seg,px)
    for (int i = tid; i < KREN * GSTRIDE; i += NTHR) gs[i] = gauss[i];
    __syncthreads();
    int q = tid & 255;          // pixel within block's row
    int seg = tid >> 8;         // gaussian segment 0..3
    int p = bid * 256 + q;
    float px = (float)(p & 255);
    float py = (float)(p >> 8);
    float cr = 0.f, cg = 0.f, cb = 0.f, acc = 0.f;
    int k0 = seg * KPER;
    for (int k = k0; k < k0 + KPER; ++k) {
      const float4* G = (const float4*)(gs + k * GSTRIDE);
      float4 g0 = G[0];
      float4 g1 = G[1];
      float g2x = gs[k * GSTRIDE + 8];
      float dx = px - g0.x, dy = py - g0.y;
      float sE = g0.z * dx * dx + g0.w * dx * dy + g1.x * dy * dy;
      float alpha = g1.y * exp2f(sE);
      float w = (1.0f - acc) * alpha;
      cr += w * g1.z; cg += w * g1.w; cb += w * g2x;
      acc += w;
    }
    comb[tid * 4 + 0] = cr;
    comb[tid * 4 + 1] = cg;
    comb[tid * 4 + 2] = cb;
    comb[tid * 4 + 3] = 1.0f - acc;   // segment transmittance
    __syncthreads();
    if (tid < 256) {
      float R = 0.f, Gc = 0.f, B = 0.f, T = 1.f;
#pragma unroll
      for (int s2 = 0; s2 < SEGN; ++s2) {
        int idx = (s2 * 256 + tid) * 4;
        R += T * comb[idx + 0];
        Gc += T * comb[idx + 1];
        B += T * comb[idx + 2];
        T *= comb[idx + 3];
      }
      out[3 * p + 0] = R;
      out[3 * p + 1] = Gc;
      out[3 * p + 2] = B;
    }
  }
}

extern "C" void kernel_launch(void* const* d_in, const int* in_sizes, int n_in,
                              void* d_out, int out_size, void* d_ws, size_t ws_size,
                              hipStream_t stream) {
  const float* positions = (const float*)d_in[0];
  const float* scales    = (const float*)d_in[1];
  const float* rotations = (const float*)d_in[2];
  const float* colors    = (const float*)d_in[3];
  const float* opacity   = (const float*)d_in[4];
  const float* colors_sh = (const float*)d_in[5];
  const float* cam       = (const float*)d_in[6];
  const float* campos    = (const float*)d_in[7];
  int N = in_sizes[0] / 3;
  int shstride = in_sizes[5] / N;  // 48

  char* ws = (char*)d_ws;
  u32* keys    = (u32*)ws;                      // 4 MB
  u64* cand    = (u64*)(ws + 4194304);          // 32 KB
  float* gauss = (float*)(ws + 4227072);        // 48 KB
  char* zr     = ws + 4276224;                  // zeroed region, 33280 B
  u32* hist1   = (u32*)zr;                      // 16 KB
  u32* hist2   = (u32*)(zr + 16384);            // 16 KB
  u32* state   = (u32*)(zr + 32768);            // 256 B
  u32* bar     = (u32*)(zr + 33024);            // 256 B
  float* out   = (float*)d_out;

  hipMemsetAsync(zr, 0, 33280, stream);

  void* args[] = {(void*)&positions, (void*)&scales, (void*)&rotations, (void*)&colors,
                  (void*)&opacity, (void*)&colors_sh, (void*)&cam, (void*)&campos,
                  (void*)&keys, (void*)&cand, (void*)&gauss,
                  (void*)&hist1, (void*)&hist2, (void*)&state, (void*)&bar,
                  (void*)&out, (void*)&N, (void*)&shstride};
  hipLaunchCooperativeKernel((const void*)k_fused, dim3(NBLK), dim3(NTHR), args, 0, stream);
}